// Round 1
// baseline (161.978 us; speedup 1.0000x reference)
//
#include <hip/hip_runtime.h>

typedef short v8s __attribute__((ext_vector_type(8)));
typedef float v4f __attribute__((ext_vector_type(4)));

#define CC 64
#define NN 4096
#define QTILE 128
#define KTILE 128
#define NKT 32          // NN / KTILE
#define NTHREADS 512
#define KT_S 72         // sKt row stride (64 c + 8 pad), 16B-aligned rows
#define VC_S 136        // sVc row stride (128 keys + 8 pad)
#define P_S  72         // per-wave P half-buffer stride (64 keys + 8 pad)

__device__ __forceinline__ unsigned short f2bf(float f) {
  unsigned int u = __builtin_bit_cast(unsigned int, f);
  u += 0x7FFFu + ((u >> 16) & 1u);   // RNE; inputs are finite
  return (unsigned short)(u >> 16);
}

__global__ __launch_bounds__(NTHREADS) void
chanattn_kernel(const float* __restrict__ x, float* __restrict__ out) {
  // 0..18432: sKt [128][72] bf16 (transposed K/Q tile)
  // 18432..35840: sVc [64][136] bf16 (direct V tile)
  // 35840..54272: sP, 8 waves x [16][72] bf16 (P half-buffer)
  // epilogue overlay: sOt [64][132] f32 at base (33792 B)
  __shared__ __align__(16) unsigned char smem[54272];
  unsigned short* sKt = (unsigned short*)smem;
  unsigned short* sVc = (unsigned short*)(smem + 18432);
  unsigned short* sP  = (unsigned short*)(smem + 35840);

  const int tid  = threadIdx.x;
  const int wave = tid >> 6;
  const int lane = tid & 63;
  const int quad = lane >> 4;
  const int l15  = lane & 15;

  const int b  = blockIdx.x & 7;   // batch -> XCD affinity
  const int qt = blockIdx.x >> 3;  // 0..31 query tile

  const float* fb = x + (size_t)b * (CC * NN);

  // staging assignment: thread -> (key = tid&127, 16 channels starting sc0)
  const int skey = tid & 127;
  const int sc0  = (tid >> 7) << 4;

  // ---- stage Q tile transposed into sKt ----
  {
    float vq[16];
#pragma unroll
    for (int j = 0; j < 16; ++j)
      vq[j] = fb[(sc0 + j) * NN + qt * QTILE + skey];
    unsigned short us[16];
#pragma unroll
    for (int j = 0; j < 16; ++j) us[j] = f2bf(vq[j]);
#pragma unroll
    for (int h = 0; h < 2; ++h) {
      v8s t;
#pragma unroll
      for (int j = 0; j < 8; ++j) t[j] = (short)us[h * 8 + j];
      *(v8s*)&sKt[skey * KT_S + sc0 + h * 8] = t;
    }
  }

  // prefetch K/V tile 0 into registers (hides under barrier + A-frag reads)
  float vk[16];
#pragma unroll
  for (int j = 0; j < 16; ++j)
    vk[j] = fb[(sc0 + j) * NN + skey];

  __syncthreads();

  // A-fragments of Q, held in registers for the whole k-loop.
  // A[m=lane&15][k=quad*8+j] (guide-verified 16x16x32 layout)
  v8s aq[2];
#pragma unroll
  for (int cs = 0; cs < 2; ++cs)
    aq[cs] = *(const v8s*)&sKt[(wave * 16 + l15) * KT_S + cs * 32 + quad * 8];

  __syncthreads();

  v4f oacc[4];
#pragma unroll
  for (int ct = 0; ct < 4; ++ct) oacc[ct] = (v4f){0.f, 0.f, 0.f, 0.f};
  float m_run[4], l_run[4];
#pragma unroll
  for (int r = 0; r < 4; ++r) { m_run[r] = -3.0e38f; l_run[r] = 0.f; }

  const float LOG2E = 1.44269504088896340736f;
  unsigned short* sPw = sP + wave * (16 * P_S);

  for (int kt = 0; kt < NKT; ++kt) {
    // ---- write prefetched K/V tile to LDS (both layouts) ----
    {
      unsigned short us[16];
#pragma unroll
      for (int j = 0; j < 16; ++j) us[j] = f2bf(vk[j]);
#pragma unroll
      for (int h = 0; h < 2; ++h) {
        v8s t;
#pragma unroll
        for (int j = 0; j < 8; ++j) t[j] = (short)us[h * 8 + j];
        *(v8s*)&sKt[skey * KT_S + sc0 + h * 8] = t;   // Kt[key][c]
      }
#pragma unroll
      for (int j = 0; j < 16; ++j)
        sVc[(sc0 + j) * VC_S + skey] = us[j];         // Vc[c][key]
    }
    __syncthreads();

    // ---- prefetch next tile (in flight during compute) ----
    if (kt + 1 < NKT) {
      const int m0 = (kt + 1) * KTILE;
#pragma unroll
      for (int j = 0; j < 16; ++j)
        vk[j] = fb[(sc0 + j) * NN + m0 + skey];
    }

    // ---- S = Q K^T : 8 key-tiles of 16, C-frag row=q(quad*4+r), col=key(l15) ----
    v4f sacc[8];
#pragma unroll
    for (int t = 0; t < 8; ++t) {
      v4f acc = (v4f){0.f, 0.f, 0.f, 0.f};
#pragma unroll
      for (int cs = 0; cs < 2; ++cs) {
        v8s bf = *(const v8s*)&sKt[(t * 16 + l15) * KT_S + cs * 32 + quad * 8];
        acc = __builtin_amdgcn_mfma_f32_16x16x32_bf16(aq[cs], bf, acc, 0, 0, 0);
      }
      sacc[t] = acc;
    }

    // ---- online softmax ----
    float alpha[4], msc[4], rsum[4];
#pragma unroll
    for (int r = 0; r < 4; ++r) {
      float mv = sacc[0][r];
#pragma unroll
      for (int t = 1; t < 8; ++t) mv = fmaxf(mv, sacc[t][r]);
      mv = fmaxf(mv, __shfl_xor(mv, 8, 64));
      mv = fmaxf(mv, __shfl_xor(mv, 4, 64));
      mv = fmaxf(mv, __shfl_xor(mv, 2, 64));
      mv = fmaxf(mv, __shfl_xor(mv, 1, 64));
      float mnew = fmaxf(m_run[r], mv);
      alpha[r] = __builtin_amdgcn_exp2f((m_run[r] - mnew) * LOG2E);
      m_run[r] = mnew;
      msc[r] = mnew * LOG2E;
      l_run[r] *= alpha[r];
      rsum[r] = 0.f;
    }
#pragma unroll
    for (int ct = 0; ct < 4; ++ct) {
#pragma unroll
      for (int r = 0; r < 4; ++r) oacc[ct][r] *= alpha[r];
    }

    // ---- half 0: P for keys 0..63 -> LDS, then PV ms=0,1 ----
#pragma unroll
    for (int t = 0; t < 4; ++t) {
#pragma unroll
      for (int r = 0; r < 4; ++r) {
        float p = __builtin_amdgcn_exp2f(__builtin_fmaf(sacc[t][r], LOG2E, -msc[r]));
        rsum[r] += p;
        sPw[(quad * 4 + r) * P_S + t * 16 + l15] = f2bf(p);
      }
    }
    asm volatile("s_waitcnt lgkmcnt(0)" ::: "memory");
#pragma unroll
    for (int ms = 0; ms < 2; ++ms) {
      v8s af = *(const v8s*)&sPw[l15 * P_S + ms * 32 + quad * 8];
#pragma unroll
      for (int ct = 0; ct < 4; ++ct) {
        v8s bf = *(const v8s*)&sVc[(ct * 16 + l15) * VC_S + ms * 32 + quad * 8];
        oacc[ct] = __builtin_amdgcn_mfma_f32_16x16x32_bf16(af, bf, oacc[ct], 0, 0, 0);
      }
    }
    asm volatile("s_waitcnt lgkmcnt(0)" ::: "memory");

    // ---- half 1: P for keys 64..127, PV ms=2,3 ----
#pragma unroll
    for (int t = 4; t < 8; ++t) {
#pragma unroll
      for (int r = 0; r < 4; ++r) {
        float p = __builtin_amdgcn_exp2f(__builtin_fmaf(sacc[t][r], LOG2E, -msc[r]));
        rsum[r] += p;
        sPw[(quad * 4 + r) * P_S + (t - 4) * 16 + l15] = f2bf(p);
      }
    }
    asm volatile("s_waitcnt lgkmcnt(0)" ::: "memory");
#pragma unroll
    for (int ms = 0; ms < 2; ++ms) {
      v8s af = *(const v8s*)&sPw[l15 * P_S + ms * 32 + quad * 8];
#pragma unroll
      for (int ct = 0; ct < 4; ++ct) {
        v8s bf = *(const v8s*)&sVc[(ct * 16 + l15) * VC_S + (2 + ms) * 32 + quad * 8];
        oacc[ct] = __builtin_amdgcn_mfma_f32_16x16x32_bf16(af, bf, oacc[ct], 0, 0, 0);
      }
    }

    // ---- fold row-sum into running l ----
#pragma unroll
    for (int r = 0; r < 4; ++r) {
      float s = rsum[r];
      s += __shfl_xor(s, 8, 64);
      s += __shfl_xor(s, 4, 64);
      s += __shfl_xor(s, 2, 64);
      s += __shfl_xor(s, 1, 64);
      l_run[r] += s;
    }
    __syncthreads();   // protect sKt/sVc for next stage
  }

  // ---- epilogue: normalize, transpose O through LDS, coalesced residual+store ----
  float inv[4];
#pragma unroll
  for (int r = 0; r < 4; ++r) inv[r] = __builtin_amdgcn_rcpf(l_run[r]);

  float* sOt = (float*)smem;   // [64 c][132] f32, overlays sKt+sVc
#pragma unroll
  for (int ct = 0; ct < 4; ++ct) {
#pragma unroll
    for (int r = 0; r < 4; ++r)
      sOt[(ct * 16 + l15) * 132 + wave * 16 + quad * 4 + r] = oacc[ct][r] * inv[r];
  }
  __syncthreads();

#pragma unroll
  for (int j = 0; j < 4; ++j) {
    int idx = tid + j * NTHREADS;     // 0..2047 over (c, n4)
    int nv = idx & 31;                // float4 index along n
    int c  = idx >> 5;                // 0..63
    float4 o = *(const float4*)&sOt[c * 132 + nv * 4];
    size_t g = (size_t)b * (CC * NN) + (size_t)c * NN + (size_t)(qt * QTILE + nv * 4);
    float4 xv = *(const float4*)(x + g);
    float4 res = make_float4(xv.x + o.x, xv.y + o.y, xv.z + o.z, xv.w + o.w);
    *(float4*)(out + g) = res;
  }
}

extern "C" void kernel_launch(void* const* d_in, const int* in_sizes, int n_in,
                              void* d_out, int out_size, void* d_ws, size_t ws_size,
                              hipStream_t stream) {
  const float* xin = (const float*)d_in[0];
  float* out = (float*)d_out;
  chanattn_kernel<<<dim3(256), dim3(NTHREADS), 0, stream>>>(xin, out);
}

// Round 2
// 120.691 us; speedup vs baseline: 1.3421x; 1.3421x over previous
//
#include <hip/hip_runtime.h>

typedef short v8s __attribute__((ext_vector_type(8)));
typedef float v4f __attribute__((ext_vector_type(4)));

#define CC 64
#define NN 4096
#define NKT 32
#define LOG2E 1.44269504088896340736f

// ---- d_ws layout (bytes) ----
#define WS_FBF_T 0u          // u16 [8][4096][64]  f transposed (n-major)
#define WS_FBF   4194304u    // u16 [8][64][4096]  f natural (c-major rows)
#define WS_G     8388608u    // f32 [8][4096]      row squared-norms
#define WS_MAXN  8519680u    // i32 [8]            per-batch max g (as int bits)
#define WS_NEED  8519712u

__device__ __forceinline__ unsigned short f2bf_rne(float f) {
  unsigned int u = __builtin_bit_cast(unsigned int, f);
  u += 0x7FFFu + ((u >> 16) & 1u);
  return (unsigned short)(u >> 16);
}

// ============ pre-pass: fp32 -> bf16 (both layouts) + row norms + batch max ============
__global__ __launch_bounds__(256) void prep_kernel(
    const float* __restrict__ x, unsigned short* __restrict__ fbf_t,
    unsigned short* __restrict__ fbf, float* __restrict__ g, int* __restrict__ maxn) {
  __shared__ unsigned short T[64 * 72];   // [n][c] bf16 tile
  __shared__ float red[16][64];
  const int t = threadIdx.x;
  const int b = blockIdx.x & 7;
  const int n0 = (blockIdx.x >> 3) << 6;
  const int nn = (t & 15) << 2;
  float ps0 = 0.f, ps1 = 0.f, ps2 = 0.f, ps3 = 0.f;
#pragma unroll
  for (int j = 0; j < 4; ++j) {
    int c = (t >> 4) + j * 16;
    size_t gidx = ((size_t)(b * 64 + c) << 12) + (unsigned)(n0 + nn);
    float4 v = *(const float4*)(x + gidx);
    ushort4 w;
    w.x = f2bf_rne(v.x); w.y = f2bf_rne(v.y); w.z = f2bf_rne(v.z); w.w = f2bf_rne(v.w);
    *(ushort4*)(fbf + gidx) = w;
    T[(nn + 0) * 72 + c] = w.x;
    T[(nn + 1) * 72 + c] = w.y;
    T[(nn + 2) * 72 + c] = w.z;
    T[(nn + 3) * 72 + c] = w.w;
    ps0 += v.x * v.x; ps1 += v.y * v.y; ps2 += v.z * v.z; ps3 += v.w * v.w;
  }
  red[t >> 4][nn + 0] = ps0; red[t >> 4][nn + 1] = ps1;
  red[t >> 4][nn + 2] = ps2; red[t >> 4][nn + 3] = ps3;
  __syncthreads();
  if (t < 64) {   // wave 0, uniform
    float gs = 0.f;
#pragma unroll
    for (int i = 0; i < 16; ++i) gs += red[i][t];
    g[b * 4096 + n0 + t] = gs;
    float m = gs;
    m = fmaxf(m, __shfl_xor(m, 1, 64));
    m = fmaxf(m, __shfl_xor(m, 2, 64));
    m = fmaxf(m, __shfl_xor(m, 4, 64));
    m = fmaxf(m, __shfl_xor(m, 8, 64));
    m = fmaxf(m, __shfl_xor(m, 16, 64));
    m = fmaxf(m, __shfl_xor(m, 32, 64));
    if (t == 0) atomicMax(maxn + b, __float_as_int(m));
  }
#pragma unroll
  for (int i = 0; i < 2; ++i) {
    int idx = t + i * 256;
    int n = idx >> 3, cs = (idx & 7) << 3;
    *(v8s*)(fbf_t + (((size_t)b << 12) + (unsigned)(n0 + n)) * 64 + cs) =
        *(const v8s*)&T[n * 72 + cs];
  }
}

// ============ main: fixed-bound flash attention, M-blocked 4x, kg key-split ============
__global__ __launch_bounds__(512, 2) void chanattn_main(
    const float* __restrict__ x, const unsigned short* __restrict__ fbf_t,
    const unsigned short* __restrict__ fbf, const float* __restrict__ g,
    const int* __restrict__ maxn, float* __restrict__ out) {
  // 0..18432      sKt u16 [128 key][72]   (c-major rows, Q then K tiles)
  // 18432..35840  sVc u16 [64 c][136]     (key-major rows, V tile)
  // 35840..56320  sP  u16 8 waves x [32][40] (P half-buffer, 2 mt rows per half)
  // overlays: Obuf f32 [2][64][68] @0 (34816); lred f32 [2][64][4] @35840 (2048)
  __shared__ __align__(16) unsigned char smem[56320];
  unsigned short* sKt = (unsigned short*)smem;
  unsigned short* sVc = (unsigned short*)(smem + 18432);
  unsigned short* sP  = (unsigned short*)(smem + 35840);

  const int tid = threadIdx.x;
  const int wave = tid >> 6, lane = tid & 63, quad = lane >> 4, l15 = lane & 15;
  const int qg = wave >> 2, kg = wave & 3;   // 2 q-groups x 4 key-groups
  const int b = blockIdx.x & 7, qt = blockIdx.x >> 3;

  const unsigned short* fT = fbf_t + (((size_t)b << 12) << 6);  // [n][c]
  const unsigned short* fV = fbf + ((size_t)b << 18);           // [c][n]

  const int sKey = tid >> 3, sC = (tid & 7) << 3;   // sKt staging (+64 key on i=1)
  const int vC = tid >> 4, vK = (tid & 15) << 3;    // sVc staging (+32 c on i=1)

  // ---- stage Q tile (rows qt*128..+127) into sKt ----
#pragma unroll
  for (int i = 0; i < 2; ++i) {
    int key = sKey + i * 64;
    *(v8s*)&sKt[key * 72 + sC] =
        *(const v8s*)&fT[((size_t)(qt * 128 + key)) * 64 + sC];
  }
  __syncthreads();
  v8s aqf[4][2];   // Q A-frags, 64 q-rows per wave, held all kernel
#pragma unroll
  for (int mt = 0; mt < 4; ++mt)
#pragma unroll
    for (int cs = 0; cs < 2; ++cs)
      aqf[mt][cs] = *(const v8s*)&sKt[(qg * 64 + mt * 16 + l15) * 72 + cs * 32 + quad * 8];

  // per-row fixed softmax bound: sqrt(g_n * gmax) (Cauchy-Schwarz), in log2 domain
  float msc[4][4];
  {
    const float gmax = __int_as_float(maxn[b]);
#pragma unroll
    for (int mt = 0; mt < 4; ++mt)
#pragma unroll
      for (int r = 0; r < 4; ++r) {
        int row = qt * 128 + qg * 64 + mt * 16 + quad * 4 + r;
        msc[mt][r] = __builtin_sqrtf(g[b * 4096 + row] * gmax) * LOG2E;
      }
  }
  __syncthreads();

  // prefetch K/V tile 0
  v8s pf[4];
#pragma unroll
  for (int i = 0; i < 2; ++i)
    pf[i] = *(const v8s*)&fT[((size_t)(sKey + i * 64)) * 64 + sC];
#pragma unroll
  for (int i = 0; i < 2; ++i)
    pf[2 + i] = *(const v8s*)&fV[(size_t)(vC + i * 32) * 4096 + vK];

  v4f oacc[4][4];
  float rsum[4][4];
#pragma unroll
  for (int mt = 0; mt < 4; ++mt)
#pragma unroll
    for (int r = 0; r < 4; ++r) {
      oacc[mt][r] = (v4f){0.f, 0.f, 0.f, 0.f};
      rsum[mt][r] = 0.f;
    }
  unsigned short* sPw = sP + wave * (32 * 40);

  for (int kt = 0; kt < NKT; ++kt) {
    // ---- write prefetched tile (both layouts, pure b128) ----
#pragma unroll
    for (int i = 0; i < 2; ++i)
      *(v8s*)&sKt[(sKey + i * 64) * 72 + sC] = pf[i];
#pragma unroll
    for (int i = 0; i < 2; ++i)
      *(v8s*)&sVc[(vC + i * 32) * 136 + vK] = pf[2 + i];
    __syncthreads();
    if (kt + 1 < NKT) {
      const int k0 = (kt + 1) * 128;
#pragma unroll
      for (int i = 0; i < 2; ++i)
        pf[i] = *(const v8s*)&fT[((size_t)(k0 + sKey + i * 64)) * 64 + sC];
#pragma unroll
      for (int i = 0; i < 2; ++i)
        pf[2 + i] = *(const v8s*)&fV[(size_t)(vC + i * 32) * 4096 + k0 + vK];
    }

    // ---- QK: wave's 32 keys, col l15 -> key 2*l15+nt (for b32 P packing) ----
    v4f sacc[4][2];
#pragma unroll
    for (int mt = 0; mt < 4; ++mt)
#pragma unroll
      for (int nt = 0; nt < 2; ++nt) sacc[mt][nt] = (v4f){0.f, 0.f, 0.f, 0.f};
#pragma unroll
    for (int nt = 0; nt < 2; ++nt)
#pragma unroll
      for (int cs = 0; cs < 2; ++cs) {
        v8s bK = *(const v8s*)&sKt[(kg * 32 + 2 * l15 + nt) * 72 + cs * 32 + quad * 8];
#pragma unroll
        for (int mt = 0; mt < 4; ++mt)
          sacc[mt][nt] =
              __builtin_amdgcn_mfma_f32_16x16x32_bf16(aqf[mt][cs], bK, sacc[mt][nt], 0, 0, 0);
      }

    // ---- fixed-bound softmax; pack adjacent-key pair to u32 (RTZ bf16) ----
    unsigned int pk[4][4];
#pragma unroll
    for (int mt = 0; mt < 4; ++mt)
#pragma unroll
      for (int r = 0; r < 4; ++r) {
        float p0 = __builtin_amdgcn_exp2f(__builtin_fmaf(sacc[mt][0][r], LOG2E, -msc[mt][r]));
        float p1 = __builtin_amdgcn_exp2f(__builtin_fmaf(sacc[mt][1][r], LOG2E, -msc[mt][r]));
        rsum[mt][r] += p0 + p1;
        unsigned int u0 = __builtin_bit_cast(unsigned int, p0);
        unsigned int u1 = __builtin_bit_cast(unsigned int, p1);
        pk[mt][r] = (u1 & 0xFFFF0000u) | (u0 >> 16);
      }

    // ---- PV: bV held across both mt-halves ----
    v8s bV[4];
#pragma unroll
    for (int ct = 0; ct < 4; ++ct)
      bV[ct] = *(const v8s*)&sVc[(ct * 16 + l15) * 136 + kg * 32 + quad * 8];
#pragma unroll
    for (int h = 0; h < 2; ++h) {
#pragma unroll
      for (int m2 = 0; m2 < 2; ++m2)
#pragma unroll
        for (int r = 0; r < 4; ++r)
          *(unsigned int*)&sPw[(m2 * 16 + quad * 4 + r) * 40 + 2 * l15] = pk[h * 2 + m2][r];
      asm volatile("s_waitcnt lgkmcnt(0)" ::: "memory");
      v8s aP[2];
#pragma unroll
      for (int m2 = 0; m2 < 2; ++m2)
        aP[m2] = *(const v8s*)&sPw[(m2 * 16 + l15) * 40 + quad * 8];
      asm volatile("s_waitcnt lgkmcnt(0)" ::: "memory");
#pragma unroll
      for (int m2 = 0; m2 < 2; ++m2)
#pragma unroll
        for (int ct = 0; ct < 4; ++ct)
          oacc[h * 2 + m2][ct] = __builtin_amdgcn_mfma_f32_16x16x32_bf16(
              aP[m2], bV[ct], oacc[h * 2 + m2][ct], 0, 0, 0);
    }
    __syncthreads();
  }

  // ---- epilogue: fold l over lanes, merge kg partials, residual store ----
#pragma unroll
  for (int mt = 0; mt < 4; ++mt)
#pragma unroll
    for (int r = 0; r < 4; ++r) {
      float s = rsum[mt][r];
      s += __shfl_xor(s, 1, 64);
      s += __shfl_xor(s, 2, 64);
      s += __shfl_xor(s, 4, 64);
      s += __shfl_xor(s, 8, 64);
      rsum[mt][r] = s;
    }
  float* lred = (float*)(smem + 35840);   // [2][64][4]
  if (l15 == 0) {
#pragma unroll
    for (int mt = 0; mt < 4; ++mt)
#pragma unroll
      for (int r = 0; r < 4; ++r)
        lred[(qg * 64 + mt * 16 + quad * 4 + r) * 4 + kg] = rsum[mt][r];
  }
  __syncthreads();
  float inv[4][4];
#pragma unroll
  for (int mt = 0; mt < 4; ++mt)
#pragma unroll
    for (int r = 0; r < 4; ++r) {
      const float4 lv = *(const float4*)&lred[(qg * 64 + mt * 16 + quad * 4 + r) * 4];
      inv[mt][r] = __builtin_amdgcn_rcpf(lv.x + lv.y + lv.z + lv.w);
    }

  float* Obuf = (float*)smem;   // [2 qg][64 c][68 q]
#pragma unroll
  for (int round = 0; round < 4; ++round) {
    if (kg == round) {
#pragma unroll
      for (int mt = 0; mt < 4; ++mt)
#pragma unroll
        for (int ct = 0; ct < 4; ++ct)
#pragma unroll
          for (int r = 0; r < 4; ++r) {
            float val = oacc[mt][ct][r] * inv[mt][r];
            float* p = &Obuf[(qg * 64 + ct * 16 + l15) * 68 + mt * 16 + quad * 4 + r];
            if (round == 0) *p = val; else *p += val;
          }
    }
    __syncthreads();
  }
#pragma unroll
  for (int j = 0; j < 4; ++j) {
    int idx = tid + j * 512;
    int qg2 = idx >> 10, c = (idx >> 4) & 63, q4 = idx & 15;
    const float4 o = *(const float4*)&Obuf[(qg2 * 64 + c) * 68 + q4 * 4];
    size_t gidx = ((size_t)(b * 64 + c) << 12) + (unsigned)(qt * 128 + qg2 * 64 + q4 * 4);
    const float4 xv = *(const float4*)(x + gidx);
    float4 rv;
    rv.x = xv.x + o.x; rv.y = xv.y + o.y; rv.z = xv.z + o.z; rv.w = xv.w + o.w;
    *(float4*)(out + gidx) = rv;
  }
}

// ============ fallback (R1 kernel, proven correct) if ws too small ============
__global__ __launch_bounds__(512) void
chanattn_fallback(const float* __restrict__ x, float* __restrict__ out) {
  __shared__ __align__(16) unsigned char smem[54272];
  unsigned short* sKt = (unsigned short*)smem;
  unsigned short* sVc = (unsigned short*)(smem + 18432);
  unsigned short* sP  = (unsigned short*)(smem + 35840);
  const int tid = threadIdx.x;
  const int wave = tid >> 6, lane = tid & 63, quad = lane >> 4, l15 = lane & 15;
  const int b = blockIdx.x & 7, qt = blockIdx.x >> 3;
  const float* fb = x + (size_t)b * (CC * NN);
  const int skey = tid & 127, sc0 = (tid >> 7) << 4;
  {
    float vq[16];
#pragma unroll
    for (int j = 0; j < 16; ++j) vq[j] = fb[(sc0 + j) * NN + qt * 128 + skey];
    unsigned short us[16];
#pragma unroll
    for (int j = 0; j < 16; ++j) us[j] = f2bf_rne(vq[j]);
#pragma unroll
    for (int h = 0; h < 2; ++h) {
      v8s t;
#pragma unroll
      for (int j = 0; j < 8; ++j) t[j] = (short)us[h * 8 + j];
      *(v8s*)&sKt[skey * 72 + sc0 + h * 8] = t;
    }
  }
  float vk[16];
#pragma unroll
  for (int j = 0; j < 16; ++j) vk[j] = fb[(sc0 + j) * NN + skey];
  __syncthreads();
  v8s aq[2];
#pragma unroll
  for (int cs = 0; cs < 2; ++cs)
    aq[cs] = *(const v8s*)&sKt[(wave * 16 + l15) * 72 + cs * 32 + quad * 8];
  __syncthreads();
  v4f oacc[4];
#pragma unroll
  for (int ct = 0; ct < 4; ++ct) oacc[ct] = (v4f){0.f, 0.f, 0.f, 0.f};
  float m_run[4], l_run[4];
#pragma unroll
  for (int r = 0; r < 4; ++r) { m_run[r] = -3.0e38f; l_run[r] = 0.f; }
  unsigned short* sPw = sP + wave * (16 * 72);
  for (int kt = 0; kt < 32; ++kt) {
    {
      unsigned short us[16];
#pragma unroll
      for (int j = 0; j < 16; ++j) us[j] = f2bf_rne(vk[j]);
#pragma unroll
      for (int h = 0; h < 2; ++h) {
        v8s t;
#pragma unroll
        for (int j = 0; j < 8; ++j) t[j] = (short)us[h * 8 + j];
        *(v8s*)&sKt[skey * 72 + sc0 + h * 8] = t;
      }
#pragma unroll
      for (int j = 0; j < 16; ++j) sVc[(sc0 + j) * 136 + skey] = us[j];
    }
    __syncthreads();
    if (kt + 1 < 32) {
      const int m0 = (kt + 1) * 128;
#pragma unroll
      for (int j = 0; j < 16; ++j) vk[j] = fb[(sc0 + j) * NN + m0 + skey];
    }
    v4f sacc[8];
#pragma unroll
    for (int t = 0; t < 8; ++t) {
      v4f acc = (v4f){0.f, 0.f, 0.f, 0.f};
#pragma unroll
      for (int cs = 0; cs < 2; ++cs) {
        v8s bf = *(const v8s*)&sKt[(t * 16 + l15) * 72 + cs * 32 + quad * 8];
        acc = __builtin_amdgcn_mfma_f32_16x16x32_bf16(aq[cs], bf, acc, 0, 0, 0);
      }
      sacc[t] = acc;
    }
    float alpha[4], msc[4], rsum[4];
#pragma unroll
    for (int r = 0; r < 4; ++r) {
      float mv = sacc[0][r];
#pragma unroll
      for (int t = 1; t < 8; ++t) mv = fmaxf(mv, sacc[t][r]);
      mv = fmaxf(mv, __shfl_xor(mv, 8, 64));
      mv = fmaxf(mv, __shfl_xor(mv, 4, 64));
      mv = fmaxf(mv, __shfl_xor(mv, 2, 64));
      mv = fmaxf(mv, __shfl_xor(mv, 1, 64));
      float mnew = fmaxf(m_run[r], mv);
      alpha[r] = __builtin_amdgcn_exp2f((m_run[r] - mnew) * LOG2E);
      m_run[r] = mnew;
      msc[r] = mnew * LOG2E;
      l_run[r] *= alpha[r];
      rsum[r] = 0.f;
    }
#pragma unroll
    for (int ct = 0; ct < 4; ++ct)
#pragma unroll
      for (int r = 0; r < 4; ++r) oacc[ct][r] *= alpha[r];
#pragma unroll
    for (int half = 0; half < 2; ++half) {
#pragma unroll
      for (int t = half * 4; t < half * 4 + 4; ++t)
#pragma unroll
        for (int r = 0; r < 4; ++r) {
          float p = __builtin_amdgcn_exp2f(__builtin_fmaf(sacc[t][r], LOG2E, -msc[r]));
          rsum[r] += p;
          sPw[(quad * 4 + r) * 72 + (t - half * 4) * 16 + l15] = f2bf_rne(p);
        }
      asm volatile("s_waitcnt lgkmcnt(0)" ::: "memory");
#pragma unroll
      for (int ms = 0; ms < 2; ++ms) {
        v8s af = *(const v8s*)&sPw[l15 * 72 + ms * 32 + quad * 8];
#pragma unroll
        for (int ct = 0; ct < 4; ++ct) {
          v8s bf = *(const v8s*)&sVc[(ct * 16 + l15) * 136 + (half * 2 + ms) * 32 + quad * 8];
          oacc[ct] = __builtin_amdgcn_mfma_f32_16x16x32_bf16(af, bf, oacc[ct], 0, 0, 0);
        }
      }
      asm volatile("s_waitcnt lgkmcnt(0)" ::: "memory");
    }
#pragma unroll
    for (int r = 0; r < 4; ++r) {
      float s = rsum[r];
      s += __shfl_xor(s, 8, 64);
      s += __shfl_xor(s, 4, 64);
      s += __shfl_xor(s, 2, 64);
      s += __shfl_xor(s, 1, 64);
      l_run[r] += s;
    }
    __syncthreads();
  }
  float inv[4];
#pragma unroll
  for (int r = 0; r < 4; ++r) inv[r] = __builtin_amdgcn_rcpf(l_run[r]);
  float* sOt = (float*)smem;
#pragma unroll
  for (int ct = 0; ct < 4; ++ct)
#pragma unroll
    for (int r = 0; r < 4; ++r)
      sOt[(ct * 16 + l15) * 132 + wave * 16 + quad * 4 + r] = oacc[ct][r] * inv[r];
  __syncthreads();
#pragma unroll
  for (int j = 0; j < 4; ++j) {
    int idx = tid + j * 512;
    int nv = idx & 31, c = idx >> 5;
    float4 o = *(const float4*)&sOt[c * 132 + nv * 4];
    size_t gaddr = (size_t)b * (CC * NN) + (size_t)c * NN + (size_t)(qt * 128 + nv * 4);
    float4 xv = *(const float4*)(x + gaddr);
    float4 res = make_float4(xv.x + o.x, xv.y + o.y, xv.z + o.z, xv.w + o.w);
    *(float4*)(out + gaddr) = res;
  }
}

extern "C" void kernel_launch(void* const* d_in, const int* in_sizes, int n_in,
                              void* d_out, int out_size, void* d_ws, size_t ws_size,
                              hipStream_t stream) {
  const float* xin = (const float*)d_in[0];
  float* out = (float*)d_out;
  if (ws_size >= (size_t)WS_NEED) {
    unsigned short* fbf_t = (unsigned short*)((char*)d_ws + WS_FBF_T);
    unsigned short* fbf = (unsigned short*)((char*)d_ws + WS_FBF);
    float* g = (float*)((char*)d_ws + WS_G);
    int* maxn = (int*)((char*)d_ws + WS_MAXN);
    hipMemsetAsync(maxn, 0, 8 * sizeof(int), stream);
    prep_kernel<<<dim3(512), dim3(256), 0, stream>>>(xin, fbf_t, fbf, g, maxn);
    chanattn_main<<<dim3(256), dim3(512), 0, stream>>>(xin, fbf_t, fbf, g, maxn, out);
  } else {
    chanattn_fallback<<<dim3(256), dim3(512), 0, stream>>>(xin, out);
  }
}

// Round 3
// 118.216 us; speedup vs baseline: 1.3702x; 1.0209x over previous
//
#include <hip/hip_runtime.h>

typedef short v8s __attribute__((ext_vector_type(8)));
typedef short v4s __attribute__((ext_vector_type(4)));
typedef float v4f __attribute__((ext_vector_type(4)));

#define LOG2E 1.44269504088896340736f

// ---- d_ws layout (bytes) ----
#define WS_FBF_T 0u          // u16 [8][4096][64]  f transposed (n-major)
#define WS_FBF   4194304u    // u16 [8][64][4096]  f natural (c-major rows)
#define WS_G     8388608u    // f32 [8][4096]      row squared-norms
#define WS_MAXN  8519680u    // i32 [8]            per-batch max g (as int bits)
#define WS_NEED  8519712u

__device__ __forceinline__ unsigned short f2bf_rne(float f) {
  unsigned int u = __builtin_bit_cast(unsigned int, f);
  u += 0x7FFFu + ((u >> 16) & 1u);
  return (unsigned short)(u >> 16);
}

// ============ pre-pass: fp32 -> bf16 (both layouts) + row norms + batch max ============
__global__ __launch_bounds__(256) void prep_kernel(
    const float* __restrict__ x, unsigned short* __restrict__ fbf_t,
    unsigned short* __restrict__ fbf, float* __restrict__ g, int* __restrict__ maxn) {
  __shared__ unsigned short T[64 * 72];   // [n][c] bf16 tile
  __shared__ float red[16][64];
  const int t = threadIdx.x;
  const int b = blockIdx.x & 7;
  const int n0 = (blockIdx.x >> 3) << 6;
  const int nn = (t & 15) << 2;
  float ps0 = 0.f, ps1 = 0.f, ps2 = 0.f, ps3 = 0.f;
#pragma unroll
  for (int j = 0; j < 4; ++j) {
    int c = (t >> 4) + j * 16;
    size_t gidx = ((size_t)(b * 64 + c) << 12) + (unsigned)(n0 + nn);
    float4 v = *(const float4*)(x + gidx);
    ushort4 w;
    w.x = f2bf_rne(v.x); w.y = f2bf_rne(v.y); w.z = f2bf_rne(v.z); w.w = f2bf_rne(v.w);
    *(ushort4*)(fbf + gidx) = w;
    T[(nn + 0) * 72 + c] = w.x;
    T[(nn + 1) * 72 + c] = w.y;
    T[(nn + 2) * 72 + c] = w.z;
    T[(nn + 3) * 72 + c] = w.w;
    ps0 += v.x * v.x; ps1 += v.y * v.y; ps2 += v.z * v.z; ps3 += v.w * v.w;
  }
  red[t >> 4][nn + 0] = ps0; red[t >> 4][nn + 1] = ps1;
  red[t >> 4][nn + 2] = ps2; red[t >> 4][nn + 3] = ps3;
  __syncthreads();
  if (t < 64) {
    float gs = 0.f;
#pragma unroll
    for (int i = 0; i < 16; ++i) gs += red[i][t];
    g[b * 4096 + n0 + t] = gs;
    float m = gs;
    m = fmaxf(m, __shfl_xor(m, 1, 64));
    m = fmaxf(m, __shfl_xor(m, 2, 64));
    m = fmaxf(m, __shfl_xor(m, 4, 64));
    m = fmaxf(m, __shfl_xor(m, 8, 64));
    m = fmaxf(m, __shfl_xor(m, 16, 64));
    m = fmaxf(m, __shfl_xor(m, 32, 64));
    if (t == 0) atomicMax(maxn + b, __float_as_int(m));
  }
#pragma unroll
  for (int i = 0; i < 2; ++i) {
    int idx = t + i * 256;
    int n = idx >> 3, cs = (idx & 7) << 3;
    *(v8s*)(fbf_t + (((size_t)b << 12) + (unsigned)(n0 + n)) * 64 + cs) =
        *(const v8s*)&T[n * 72 + cs];
  }
}

// ============ main: S^T/O^T operand-swap flash attention, no P LDS round-trip ============
// Wave w: qg=w>>2 (64 q-rows, 4 q-tiles static B), kg=w&3 (32 keys).
// QK: S^T = mfma(A=K, B=Q)  -> C col=q(l15), row=key(quad*4+r)
// PV: O^T = mfma(A=V^T, B=P^T); P^T B-frag comes straight from S^T C-regs;
//     V's key-dim stored permuted: LDS slot quad*8+j holds key quad*4+j+(j>=4?12:0).
__global__ __launch_bounds__(512, 2) void chanattn_main(
    const float* __restrict__ x, const unsigned short* __restrict__ fbf_t,
    const unsigned short* __restrict__ fbf, const float* __restrict__ g,
    const int* __restrict__ maxn, float* __restrict__ out) {
  // 0..18432      sKt u16 [128 key][72]  (c-major rows; Q staged here first)
  // 18432..35840  sVc u16 [64 c][136]    (key-major rows, key-permuted)
  // 35840..37888  lred f32 [128][4]
  // epilogue overlay: Obuf f32 [2][64][68] @0 (34816 B)
  __shared__ __align__(16) unsigned char smem[37888];
  unsigned short* sKt = (unsigned short*)smem;
  unsigned short* sVc = (unsigned short*)(smem + 18432);
  float* lred = (float*)(smem + 35840);

  const int tid = threadIdx.x;
  const int wave = tid >> 6, lane = tid & 63, quad = lane >> 4, l15 = lane & 15;
  const int qg = wave >> 2, kg = wave & 3;
  const int b = blockIdx.x & 7, qt = blockIdx.x >> 3;

  const unsigned short* fT = fbf_t + ((size_t)b << 18);  // [n][c]
  const unsigned short* fV = fbf + ((size_t)b << 18);    // [c][n]

  const int sKey = tid >> 3, sC = (tid & 7) << 3;  // sKt staging (+64 key on i=1)
  const int vC = tid >> 4, vK = (tid & 15) << 3;   // sVc staging (+32 c on i=1)
  // permuted slot base for this thread's 8 keys (two b64 runs: vSlot, vSlot+8)
  const int vSlot = (vK & ~31) + ((vK & 8) ? 16 : 0) + ((vK & 16) ? 4 : 0);

  // ---- stage Q tile into sKt ----
#pragma unroll
  for (int i = 0; i < 2; ++i)
    *(v8s*)&sKt[(sKey + i * 64) * 72 + sC] =
        *(const v8s*)&fT[(size_t)(qt * 128 + sKey + i * 64) * 64 + sC];

  // issue K/V tile-0 global loads (independent of sKt)
  v8s pfk[2], pfv[2];
#pragma unroll
  for (int i = 0; i < 2; ++i)
    pfk[i] = *(const v8s*)&fT[(size_t)(sKey + i * 64) * 64 + sC];
#pragma unroll
  for (int i = 0; i < 2; ++i)
    pfv[i] = *(const v8s*)&fV[(size_t)(vC + i * 32) * 4096 + vK];

  __syncthreads();
  // Q B-frags: B[k=c][n=q], n=l15, k=quad*8+j — static for whole kernel
  v8s bQ[4][2];
#pragma unroll
  for (int jq = 0; jq < 4; ++jq)
#pragma unroll
    for (int cs = 0; cs < 2; ++cs)
      bQ[jq][cs] = *(const v8s*)&sKt[(qg * 64 + jq * 16 + l15) * 72 + cs * 32 + quad * 8];

  // per-q fixed softmax bound sqrt(g_q * gmax) (Cauchy-Schwarz), log2 domain
  float msc[4];
  {
    const float gmax = __int_as_float(maxn[b]);
#pragma unroll
    for (int jq = 0; jq < 4; ++jq) {
      int row = qt * 128 + qg * 64 + jq * 16 + l15;
      msc[jq] = __builtin_sqrtf(g[b * 4096 + row] * gmax) * LOG2E;
    }
  }
  __syncthreads();

  // write tile 0 to LDS
#pragma unroll
  for (int i = 0; i < 2; ++i)
    *(v8s*)&sKt[(sKey + i * 64) * 72 + sC] = pfk[i];
#pragma unroll
  for (int i = 0; i < 2; ++i) {
    v4s lo, hi;
#pragma unroll
    for (int j = 0; j < 4; ++j) { lo[j] = pfv[i][j]; hi[j] = pfv[i][j + 4]; }
    *(v4s*)&sVc[(vC + i * 32) * 136 + vSlot] = lo;
    *(v4s*)&sVc[(vC + i * 32) * 136 + vSlot + 8] = hi;
  }

  v4f oacc[4][4];   // [ct][jq]: O^T, col=q(l15), row=c(quad*4+r) within ct
  float rsum[4];
#pragma unroll
  for (int ct = 0; ct < 4; ++ct)
#pragma unroll
    for (int jq = 0; jq < 4; ++jq) oacc[ct][jq] = (v4f){0.f, 0.f, 0.f, 0.f};
#pragma unroll
  for (int jq = 0; jq < 4; ++jq) rsum[jq] = 0.f;

  for (int kt = 0; kt < 32; ++kt) {
    __syncthreads();   // tile kt writes visible

    // global prefetch of tile kt+1 (in flight across compute)
    if (kt + 1 < 32) {
      const int k0 = (kt + 1) * 128;
#pragma unroll
      for (int i = 0; i < 2; ++i)
        pfk[i] = *(const v8s*)&fT[(size_t)(k0 + sKey + i * 64) * 64 + sC];
#pragma unroll
      for (int i = 0; i < 2; ++i)
        pfv[i] = *(const v8s*)&fV[(size_t)(vC + i * 32) * 4096 + k0 + vK];
    }

    // LDS frag reads for this tile (all reads happen before barrier2)
    v8s aK[2][2];   // A[m=key][k=c], m=l15 (key row), k=quad*8+j
#pragma unroll
    for (int t = 0; t < 2; ++t)
#pragma unroll
      for (int cs = 0; cs < 2; ++cs)
        aK[t][cs] =
            *(const v8s*)&sKt[(kg * 32 + t * 16 + l15) * 72 + cs * 32 + quad * 8];
    v8s aV[4];      // A[m=c][k=key(permuted)], m=l15 within ct
#pragma unroll
    for (int ct = 0; ct < 4; ++ct)
      aV[ct] = *(const v8s*)&sVc[(ct * 16 + l15) * 136 + kg * 32 + quad * 8];

    __syncthreads();   // all reads done -> next-tile writes may start

    // write tile kt+1 (shares barrier-free region with compute below)
    if (kt + 1 < 32) {
#pragma unroll
      for (int i = 0; i < 2; ++i)
        *(v8s*)&sKt[(sKey + i * 64) * 72 + sC] = pfk[i];
#pragma unroll
      for (int i = 0; i < 2; ++i) {
        v4s lo, hi;
#pragma unroll
        for (int j = 0; j < 4; ++j) { lo[j] = pfv[i][j]; hi[j] = pfv[i][j + 4]; }
        *(v4s*)&sVc[(vC + i * 32) * 136 + vSlot] = lo;
        *(v4s*)&sVc[(vC + i * 32) * 136 + vSlot + 8] = hi;
      }
    }

    // ---- compute: QK -> exp2/pack -> PV, per q-tile ----
#pragma unroll
    for (int jq = 0; jq < 4; ++jq) {
      v4f s0 = (v4f){0.f, 0.f, 0.f, 0.f};
      v4f s1 = (v4f){0.f, 0.f, 0.f, 0.f};
#pragma unroll
      for (int cs = 0; cs < 2; ++cs) {
        s0 = __builtin_amdgcn_mfma_f32_16x16x32_bf16(aK[0][cs], bQ[jq][cs], s0, 0, 0, 0);
        s1 = __builtin_amdgcn_mfma_f32_16x16x32_bf16(aK[1][cs], bQ[jq][cs], s1, 0, 0, 0);
      }
      float p0[4], p1[4];
#pragma unroll
      for (int r = 0; r < 4; ++r) {
        p0[r] = __builtin_amdgcn_exp2f(__builtin_fmaf(s0[r], LOG2E, -msc[jq]));
        p1[r] = __builtin_amdgcn_exp2f(__builtin_fmaf(s1[r], LOG2E, -msc[jq]));
      }
      rsum[jq] += ((p0[0] + p0[1]) + (p0[2] + p0[3])) +
                  ((p1[0] + p1[1]) + (p1[2] + p1[3]));
      // RTZ-pack P^T B-frag: slots 0..3 = tile0 regs, 4..7 = tile1 regs
      uint4 up;
      up.x = (__builtin_bit_cast(unsigned int, p0[1]) & 0xFFFF0000u) |
             (__builtin_bit_cast(unsigned int, p0[0]) >> 16);
      up.y = (__builtin_bit_cast(unsigned int, p0[3]) & 0xFFFF0000u) |
             (__builtin_bit_cast(unsigned int, p0[2]) >> 16);
      up.z = (__builtin_bit_cast(unsigned int, p1[1]) & 0xFFFF0000u) |
             (__builtin_bit_cast(unsigned int, p1[0]) >> 16);
      up.w = (__builtin_bit_cast(unsigned int, p1[3]) & 0xFFFF0000u) |
             (__builtin_bit_cast(unsigned int, p1[2]) >> 16);
      v8s bp = __builtin_bit_cast(v8s, up);
#pragma unroll
      for (int ct = 0; ct < 4; ++ct)
        oacc[ct][jq] =
            __builtin_amdgcn_mfma_f32_16x16x32_bf16(aV[ct], bp, oacc[ct][jq], 0, 0, 0);
    }
  }

  // ---- epilogue: reduce l across quads + kg waves, merge O^T partials, store ----
#pragma unroll
  for (int jq = 0; jq < 4; ++jq) {
    float s = rsum[jq];
    s += __shfl_xor(s, 16, 64);
    s += __shfl_xor(s, 32, 64);
    rsum[jq] = s;
  }
  if (quad == 0) {
#pragma unroll
    for (int jq = 0; jq < 4; ++jq)
      lred[(qg * 64 + jq * 16 + l15) * 4 + kg] = rsum[jq];
  }
  __syncthreads();
  float inv[4];
#pragma unroll
  for (int jq = 0; jq < 4; ++jq) {
    const float4 lv = *(const float4*)&lred[(qg * 64 + jq * 16 + l15) * 4];
    inv[jq] = __builtin_amdgcn_rcpf((lv.x + lv.y) + (lv.z + lv.w));
  }

  float* Obuf = (float*)smem;   // [2 qg][64 c][68 q]
#pragma unroll
  for (int round = 0; round < 4; ++round) {
    if (kg == round) {
#pragma unroll
      for (int ct = 0; ct < 4; ++ct)
#pragma unroll
        for (int jq = 0; jq < 4; ++jq)
#pragma unroll
          for (int r = 0; r < 4; ++r) {
            float val = oacc[ct][jq][r] * inv[jq];
            float* p = &Obuf[(qg * 64 + ct * 16 + quad * 4 + r) * 68 + jq * 16 + l15];
            if (round == 0) *p = val; else *p += val;
          }
    }
    __syncthreads();
  }
#pragma unroll
  for (int j = 0; j < 4; ++j) {
    int idx = tid + j * 512;
    int qg2 = idx >> 10, c = (idx >> 4) & 63, q4 = idx & 15;
    const float4 o = *(const float4*)&Obuf[(qg2 * 64 + c) * 68 + q4 * 4];
    size_t gidx = ((size_t)(b * 64 + c) << 12) + (unsigned)(qt * 128 + qg2 * 64 + q4 * 4);
    const float4 xv = *(const float4*)(x + gidx);
    float4 rv;
    rv.x = xv.x + o.x; rv.y = xv.y + o.y; rv.z = xv.z + o.z; rv.w = xv.w + o.w;
    *(float4*)(out + gidx) = rv;
  }
}

// ============ fallback (R1 kernel, proven correct) if ws too small ============
__global__ __launch_bounds__(512) void
chanattn_fallback(const float* __restrict__ x, float* __restrict__ out) {
  __shared__ __align__(16) unsigned char smem[54272];
  unsigned short* sKt = (unsigned short*)smem;
  unsigned short* sVc = (unsigned short*)(smem + 18432);
  unsigned short* sP  = (unsigned short*)(smem + 35840);
  const int tid = threadIdx.x;
  const int wave = tid >> 6, lane = tid & 63, quad = lane >> 4, l15 = lane & 15;
  const int b = blockIdx.x & 7, qt = blockIdx.x >> 3;
  const float* fb = x + (size_t)b * (64 * 4096);
  const int skey = tid & 127, sc0 = (tid >> 7) << 4;
  {
    float vq[16];
#pragma unroll
    for (int j = 0; j < 16; ++j) vq[j] = fb[(sc0 + j) * 4096 + qt * 128 + skey];
    unsigned short us[16];
#pragma unroll
    for (int j = 0; j < 16; ++j) us[j] = f2bf_rne(vq[j]);
#pragma unroll
    for (int h = 0; h < 2; ++h) {
      v8s t;
#pragma unroll
      for (int j = 0; j < 8; ++j) t[j] = (short)us[h * 8 + j];
      *(v8s*)&sKt[skey * 72 + sc0 + h * 8] = t;
    }
  }
  float vk[16];
#pragma unroll
  for (int j = 0; j < 16; ++j) vk[j] = fb[(sc0 + j) * 4096 + skey];
  __syncthreads();
  v8s aq[2];
#pragma unroll
  for (int cs = 0; cs < 2; ++cs)
    aq[cs] = *(const v8s*)&sKt[(wave * 16 + l15) * 72 + cs * 32 + quad * 8];
  __syncthreads();
  v4f oacc[4];
#pragma unroll
  for (int ct = 0; ct < 4; ++ct) oacc[ct] = (v4f){0.f, 0.f, 0.f, 0.f};
  float m_run[4], l_run[4];
#pragma unroll
  for (int r = 0; r < 4; ++r) { m_run[r] = -3.0e38f; l_run[r] = 0.f; }
  unsigned short* sPw = sP + wave * (16 * 72);
  for (int kt = 0; kt < 32; ++kt) {
    {
      unsigned short us[16];
#pragma unroll
      for (int j = 0; j < 16; ++j) us[j] = f2bf_rne(vk[j]);
#pragma unroll
      for (int h = 0; h < 2; ++h) {
        v8s t;
#pragma unroll
        for (int j = 0; j < 8; ++j) t[j] = (short)us[h * 8 + j];
        *(v8s*)&sKt[skey * 72 + sc0 + h * 8] = t;
      }
#pragma unroll
      for (int j = 0; j < 16; ++j) sVc[(sc0 + j) * 136 + skey] = us[j];
    }
    __syncthreads();
    if (kt + 1 < 32) {
      const int m0 = (kt + 1) * 128;
#pragma unroll
      for (int j = 0; j < 16; ++j) vk[j] = fb[(sc0 + j) * 4096 + m0 + skey];
    }
    v4f sacc[8];
#pragma unroll
    for (int t = 0; t < 8; ++t) {
      v4f acc = (v4f){0.f, 0.f, 0.f, 0.f};
#pragma unroll
      for (int cs = 0; cs < 2; ++cs) {
        v8s bf = *(const v8s*)&sKt[(t * 16 + l15) * 72 + cs * 32 + quad * 8];
        acc = __builtin_amdgcn_mfma_f32_16x16x32_bf16(aq[cs], bf, acc, 0, 0, 0);
      }
      sacc[t] = acc;
    }
    float alpha[4], msc[4], rsum[4];
#pragma unroll
    for (int r = 0; r < 4; ++r) {
      float mv = sacc[0][r];
#pragma unroll
      for (int t = 1; t < 8; ++t) mv = fmaxf(mv, sacc[t][r]);
      mv = fmaxf(mv, __shfl_xor(mv, 8, 64));
      mv = fmaxf(mv, __shfl_xor(mv, 4, 64));
      mv = fmaxf(mv, __shfl_xor(mv, 2, 64));
      mv = fmaxf(mv, __shfl_xor(mv, 1, 64));
      float mnew = fmaxf(m_run[r], mv);
      alpha[r] = __builtin_amdgcn_exp2f((m_run[r] - mnew) * LOG2E);
      m_run[r] = mnew;
      msc[r] = mnew * LOG2E;
      l_run[r] *= alpha[r];
      rsum[r] = 0.f;
    }
#pragma unroll
    for (int ct = 0; ct < 4; ++ct)
#pragma unroll
      for (int r = 0; r < 4; ++r) oacc[ct][r] *= alpha[r];
#pragma unroll
    for (int half = 0; half < 2; ++half) {
#pragma unroll
      for (int t = half * 4; t < half * 4 + 4; ++t)
#pragma unroll
        for (int r = 0; r < 4; ++r) {
          float p = __builtin_amdgcn_exp2f(__builtin_fmaf(sacc[t][r], LOG2E, -msc[r]));
          rsum[r] += p;
          sPw[(quad * 4 + r) * 72 + (t - half * 4) * 16 + l15] = f2bf_rne(p);
        }
      asm volatile("s_waitcnt lgkmcnt(0)" ::: "memory");
#pragma unroll
      for (int ms = 0; ms < 2; ++ms) {
        v8s af = *(const v8s*)&sPw[l15 * 72 + ms * 32 + quad * 8];
#pragma unroll
        for (int ct = 0; ct < 4; ++ct) {
          v8s bf = *(const v8s*)&sVc[(ct * 16 + l15) * 136 + (half * 2 + ms) * 32 + quad * 8];
          oacc[ct] = __builtin_amdgcn_mfma_f32_16x16x32_bf16(af, bf, oacc[ct], 0, 0, 0);
        }
      }
      asm volatile("s_waitcnt lgkmcnt(0)" ::: "memory");
    }
#pragma unroll
    for (int r = 0; r < 4; ++r) {
      float s = rsum[r];
      s += __shfl_xor(s, 8, 64);
      s += __shfl_xor(s, 4, 64);
      s += __shfl_xor(s, 2, 64);
      s += __shfl_xor(s, 1, 64);
      l_run[r] += s;
    }
    __syncthreads();
  }
  float inv[4];
#pragma unroll
  for (int r = 0; r < 4; ++r) inv[r] = __builtin_amdgcn_rcpf(l_run[r]);
  float* sOt = (float*)smem;
#pragma unroll
  for (int ct = 0; ct < 4; ++ct)
#pragma unroll
    for (int r = 0; r < 4; ++r)
      sOt[(ct * 16 + l15) * 132 + wave * 16 + quad * 4 + r] = oacc[ct][r] * inv[r];
  __syncthreads();
#pragma unroll
  for (int j = 0; j < 4; ++j) {
    int idx = tid + j * 512;
    int nv = idx & 31, c = idx >> 5;
    float4 o = *(const float4*)&sOt[c * 132 + nv * 4];
    size_t gaddr = (size_t)b * (64 * 4096) + (size_t)c * 4096 + (size_t)(qt * 128 + nv * 4);
    float4 xv = *(const float4*)(x + gaddr);
    float4 res = make_float4(xv.x + o.x, xv.y + o.y, xv.z + o.z, xv.w + o.w);
    *(float4*)(out + gaddr) = res;
  }
}

extern "C" void kernel_launch(void* const* d_in, const int* in_sizes, int n_in,
                              void* d_out, int out_size, void* d_ws, size_t ws_size,
                              hipStream_t stream) {
  const float* xin = (const float*)d_in[0];
  float* out = (float*)d_out;
  if (ws_size >= (size_t)WS_NEED) {
    unsigned short* fbf_t = (unsigned short*)((char*)d_ws + WS_FBF_T);
    unsigned short* fbf = (unsigned short*)((char*)d_ws + WS_FBF);
    float* g = (float*)((char*)d_ws + WS_G);
    int* maxn = (int*)((char*)d_ws + WS_MAXN);
    hipMemsetAsync(maxn, 0, 8 * sizeof(int), stream);
    prep_kernel<<<dim3(512), dim3(256), 0, stream>>>(xin, fbf_t, fbf, g, maxn);
    chanattn_main<<<dim3(256), dim3(512), 0, stream>>>(xin, fbf_t, fbf, g, maxn, out);
  } else {
    chanattn_fallback<<<dim3(256), dim3(512), 0, stream>>>(xin, out);
  }
}

// Round 5
// 105.015 us; speedup vs baseline: 1.5424x; 1.1257x over previous
//
#include <hip/hip_runtime.h>

typedef short v8s __attribute__((ext_vector_type(8)));
typedef short v4s __attribute__((ext_vector_type(4)));
typedef float v4f __attribute__((ext_vector_type(4)));

#define LOG2E 1.44269504088896340736f

// ---- d_ws layout (bytes) ----
#define WS_FBF_T 0u          // u16 [8][4096][64]  f transposed (n-major)
#define WS_FBF   4194304u    // u16 [8][64][4096]  f natural (c-major rows)
#define WS_G     8388608u    // f32 [8][4096]      row squared-norms
#define WS_BMAX  8519680u    // f32 [8][64]        per-block partial max of g
#define WS_NEED  8521728u

__device__ __forceinline__ unsigned short f2bf_rne(float f) {
  unsigned int u = __builtin_bit_cast(unsigned int, f);
  u += 0x7FFFu + ((u >> 16) & 1u);
  return (unsigned short)(u >> 16);
}

// ============ pre-pass: fp32 -> bf16 (both layouts) + row norms + block max ============
__global__ __launch_bounds__(256) void prep_kernel(
    const float* __restrict__ x, unsigned short* __restrict__ fbf_t,
    unsigned short* __restrict__ fbf, float* __restrict__ g, float* __restrict__ bmax) {
  __shared__ unsigned short T[64 * 72];   // [n][c] bf16 tile
  __shared__ float red[16][64];
  const int t = threadIdx.x;
  const int b = blockIdx.x & 7;
  const int n0 = (blockIdx.x >> 3) << 6;
  const int nn = (t & 15) << 2;
  float ps0 = 0.f, ps1 = 0.f, ps2 = 0.f, ps3 = 0.f;
#pragma unroll
  for (int j = 0; j < 4; ++j) {
    int c = (t >> 4) + j * 16;
    size_t gidx = ((size_t)(b * 64 + c) << 12) + (unsigned)(n0 + nn);
    float4 v = *(const float4*)(x + gidx);
    ushort4 w;
    w.x = f2bf_rne(v.x); w.y = f2bf_rne(v.y); w.z = f2bf_rne(v.z); w.w = f2bf_rne(v.w);
    *(ushort4*)(fbf + gidx) = w;
    T[(nn + 0) * 72 + c] = w.x;
    T[(nn + 1) * 72 + c] = w.y;
    T[(nn + 2) * 72 + c] = w.z;
    T[(nn + 3) * 72 + c] = w.w;
    ps0 += v.x * v.x; ps1 += v.y * v.y; ps2 += v.z * v.z; ps3 += v.w * v.w;
  }
  red[t >> 4][nn + 0] = ps0; red[t >> 4][nn + 1] = ps1;
  red[t >> 4][nn + 2] = ps2; red[t >> 4][nn + 3] = ps3;
  __syncthreads();
  if (t < 64) {
    float gs = 0.f;
#pragma unroll
    for (int i = 0; i < 16; ++i) gs += red[i][t];
    g[b * 4096 + n0 + t] = gs;
    float m = gs;
    m = fmaxf(m, __shfl_xor(m, 1, 64));
    m = fmaxf(m, __shfl_xor(m, 2, 64));
    m = fmaxf(m, __shfl_xor(m, 4, 64));
    m = fmaxf(m, __shfl_xor(m, 8, 64));
    m = fmaxf(m, __shfl_xor(m, 16, 64));
    m = fmaxf(m, __shfl_xor(m, 32, 64));
    if (t == 0) bmax[b * 64 + (blockIdx.x >> 3)] = m;
  }
#pragma unroll
  for (int i = 0; i < 2; ++i) {
    int idx = t + i * 256;
    int n = idx >> 3, cs = (idx & 7) << 3;
    *(v8s*)(fbf_t + (((size_t)b << 12) + (unsigned)(n0 + n)) * 64 + cs) =
        *(const v8s*)&T[n * 72 + cs];
  }
}

// ============ main: S^T/O^T operand-swap flash attention ============
// Double-buffered LDS (base ptr + element offset; NO pointer arrays into LDS),
// 1 barrier/iter, depth-2 global prefetch so the barrier's vmcnt drain only
// sees loads issued a full iteration earlier.
__global__ __launch_bounds__(512, 2) void chanattn_main(
    const float* __restrict__ x, const unsigned short* __restrict__ fbf_t,
    const unsigned short* __restrict__ fbf, const float* __restrict__ g,
    const float* __restrict__ bmax, float* __restrict__ out) {
  // buf p (p=0,1; +p*17920 u16): sKt u16[128][72] @0 ; sVc u16[64][136] @+9216 u16
  // lred f32[128][4] @71680 B ; epilogue overlay Obuf f32[2][64][68] @0
  __shared__ __align__(16) unsigned char smem[73728];
  unsigned short* sKtB = (unsigned short*)smem;
  unsigned short* sVcB = (unsigned short*)(smem + 18432);
  float* lred = (float*)(smem + 71680);
  const int BUF = 17920;   // u16 elements between buffers (35840 B)

  const int tid = threadIdx.x;
  const int wave = tid >> 6, lane = tid & 63, quad = lane >> 4, l15 = lane & 15;
  const int qg = wave >> 2, kg = wave & 3;
  const int b = blockIdx.x & 7, qt = blockIdx.x >> 3;

  const unsigned short* fT = fbf_t + ((size_t)b << 18);  // [n][c]
  const unsigned short* fV = fbf + ((size_t)b << 18);    // [c][n]

  const int sKey = tid >> 3, sC = (tid & 7) << 3;  // sKt staging (+64 key on i=1)
  const int vC = tid >> 4, vK = (tid & 15) << 3;   // sVc staging (+32 c on i=1)
  const int vSlot = (vK & ~31) + ((vK & 8) ? 16 : 0) + ((vK & 16) ? 4 : 0);

  // batch gmax: every wave reduces the 64 partials itself (no atomics/memset)
  float gm = bmax[b * 64 + lane];
  gm = fmaxf(gm, __shfl_xor(gm, 1, 64));
  gm = fmaxf(gm, __shfl_xor(gm, 2, 64));
  gm = fmaxf(gm, __shfl_xor(gm, 4, 64));
  gm = fmaxf(gm, __shfl_xor(gm, 8, 64));
  gm = fmaxf(gm, __shfl_xor(gm, 16, 64));
  gm = fmaxf(gm, __shfl_xor(gm, 32, 64));
  float gq[4];
#pragma unroll
  for (int jq = 0; jq < 4; ++jq)
    gq[jq] = g[b * 4096 + qt * 128 + qg * 64 + jq * 16 + l15];

  // ---- stage Q tile into buf0 sKt ----
#pragma unroll
  for (int i = 0; i < 2; ++i)
    *(v8s*)&sKtB[(sKey + i * 64) * 72 + sC] =
        *(const v8s*)&fT[(size_t)(qt * 128 + sKey + i * 64) * 64 + sC];
  // issue tile-0 loads
  v8s pfk[2], pfv[2];
#pragma unroll
  for (int i = 0; i < 2; ++i)
    pfk[i] = *(const v8s*)&fT[(size_t)(sKey + i * 64) * 64 + sC];
#pragma unroll
  for (int i = 0; i < 2; ++i)
    pfv[i] = *(const v8s*)&fV[(size_t)(vC + i * 32) * 4096 + vK];

  __syncthreads();
  v8s bQ[4][2];   // Q B-frags, static all kernel
#pragma unroll
  for (int jq = 0; jq < 4; ++jq)
#pragma unroll
    for (int cs = 0; cs < 2; ++cs)
      bQ[jq][cs] = *(const v8s*)&sKtB[(qg * 64 + jq * 16 + l15) * 72 + cs * 32 + quad * 8];
  float msc[4];
#pragma unroll
  for (int jq = 0; jq < 4; ++jq) msc[jq] = __builtin_sqrtf(gq[jq] * gm) * LOG2E;
  __syncthreads();   // bQ reads done -> buf0 reusable

  // write tile 0 -> buf0; issue tile-1 loads
#pragma unroll
  for (int i = 0; i < 2; ++i)
    *(v8s*)&sKtB[(sKey + i * 64) * 72 + sC] = pfk[i];
#pragma unroll
  for (int i = 0; i < 2; ++i) {
    v4s lo, hi;
#pragma unroll
    for (int j = 0; j < 4; ++j) { lo[j] = pfv[i][j]; hi[j] = pfv[i][j + 4]; }
    *(v4s*)&sVcB[(vC + i * 32) * 136 + vSlot] = lo;
    *(v4s*)&sVcB[(vC + i * 32) * 136 + vSlot + 8] = hi;
  }
#pragma unroll
  for (int i = 0; i < 2; ++i)
    pfk[i] = *(const v8s*)&fT[(size_t)(128 + sKey + i * 64) * 64 + sC];
#pragma unroll
  for (int i = 0; i < 2; ++i)
    pfv[i] = *(const v8s*)&fV[(size_t)(vC + i * 32) * 4096 + 128 + vK];

  v4f oacc[4][4];
  float rsum[4];
#pragma unroll
  for (int ct = 0; ct < 4; ++ct)
#pragma unroll
    for (int jq = 0; jq < 4; ++jq) oacc[ct][jq] = (v4f){0.f, 0.f, 0.f, 0.f};
#pragma unroll
  for (int jq = 0; jq < 4; ++jq) rsum[jq] = 0.f;

  for (int kt = 0; kt < 32; ++kt) {
    __syncthreads();   // buf[kt&1] (tile kt) visible; prior reads of other buf done
    const int po = (kt & 1) * BUF;
    const int pn = ((kt & 1) ^ 1) * BUF;

    // LDS frag reads for tile kt
    v8s aK[2][2];
#pragma unroll
    for (int t = 0; t < 2; ++t)
#pragma unroll
      for (int cs = 0; cs < 2; ++cs)
        aK[t][cs] =
            *(const v8s*)&sKtB[po + (kg * 32 + t * 16 + l15) * 72 + cs * 32 + quad * 8];
    v8s aV[4];
#pragma unroll
    for (int ct = 0; ct < 4; ++ct)
      aV[ct] = *(const v8s*)&sVcB[po + (ct * 16 + l15) * 136 + kg * 32 + quad * 8];

    // ---- compute jq=0 first: MFMA in flight before any vmcnt wait ----
    {
      const int jq = 0;
      v4f s0 = (v4f){0.f, 0.f, 0.f, 0.f}, s1 = (v4f){0.f, 0.f, 0.f, 0.f};
#pragma unroll
      for (int cs = 0; cs < 2; ++cs) {
        s0 = __builtin_amdgcn_mfma_f32_16x16x32_bf16(aK[0][cs], bQ[jq][cs], s0, 0, 0, 0);
        s1 = __builtin_amdgcn_mfma_f32_16x16x32_bf16(aK[1][cs], bQ[jq][cs], s1, 0, 0, 0);
      }
      float p0[4], p1[4];
#pragma unroll
      for (int r = 0; r < 4; ++r) {
        p0[r] = __builtin_amdgcn_exp2f(__builtin_fmaf(s0[r], LOG2E, -msc[jq]));
        p1[r] = __builtin_amdgcn_exp2f(__builtin_fmaf(s1[r], LOG2E, -msc[jq]));
      }
      rsum[jq] += ((p0[0] + p0[1]) + (p0[2] + p0[3])) +
                  ((p1[0] + p1[1]) + (p1[2] + p1[3]));
      uint4 up;
      up.x = (__builtin_bit_cast(unsigned int, p0[1]) & 0xFFFF0000u) |
             (__builtin_bit_cast(unsigned int, p0[0]) >> 16);
      up.y = (__builtin_bit_cast(unsigned int, p0[3]) & 0xFFFF0000u) |
             (__builtin_bit_cast(unsigned int, p0[2]) >> 16);
      up.z = (__builtin_bit_cast(unsigned int, p1[1]) & 0xFFFF0000u) |
             (__builtin_bit_cast(unsigned int, p1[0]) >> 16);
      up.w = (__builtin_bit_cast(unsigned int, p1[3]) & 0xFFFF0000u) |
             (__builtin_bit_cast(unsigned int, p1[2]) >> 16);
      v8s bp = __builtin_bit_cast(v8s, up);
#pragma unroll
      for (int ct = 0; ct < 4; ++ct)
        oacc[ct][jq] =
            __builtin_amdgcn_mfma_f32_16x16x32_bf16(aV[ct], bp, oacc[ct][jq], 0, 0, 0);
    }

    // ---- staging writes for tile kt+1 (other buffer), then issue tile kt+2 loads ----
    if (kt < 31) {
#pragma unroll
      for (int i = 0; i < 2; ++i)
        *(v8s*)&sKtB[pn + (sKey + i * 64) * 72 + sC] = pfk[i];
#pragma unroll
      for (int i = 0; i < 2; ++i) {
        v4s lo, hi;
#pragma unroll
        for (int j = 0; j < 4; ++j) { lo[j] = pfv[i][j]; hi[j] = pfv[i][j + 4]; }
        *(v4s*)&sVcB[pn + (vC + i * 32) * 136 + vSlot] = lo;
        *(v4s*)&sVcB[pn + (vC + i * 32) * 136 + vSlot + 8] = hi;
      }
    }
    if (kt < 30) {
      const int k0 = (kt + 2) << 7;
#pragma unroll
      for (int i = 0; i < 2; ++i)
        pfk[i] = *(const v8s*)&fT[(size_t)(k0 + sKey + i * 64) * 64 + sC];
#pragma unroll
      for (int i = 0; i < 2; ++i)
        pfv[i] = *(const v8s*)&fV[(size_t)(vC + i * 32) * 4096 + k0 + vK];
    }

    // ---- remaining q-tiles ----
#pragma unroll
    for (int jq = 1; jq < 4; ++jq) {
      v4f s0 = (v4f){0.f, 0.f, 0.f, 0.f}, s1 = (v4f){0.f, 0.f, 0.f, 0.f};
#pragma unroll
      for (int cs = 0; cs < 2; ++cs) {
        s0 = __builtin_amdgcn_mfma_f32_16x16x32_bf16(aK[0][cs], bQ[jq][cs], s0, 0, 0, 0);
        s1 = __builtin_amdgcn_mfma_f32_16x16x32_bf16(aK[1][cs], bQ[jq][cs], s1, 0, 0, 0);
      }
      float p0[4], p1[4];
#pragma unroll
      for (int r = 0; r < 4; ++r) {
        p0[r] = __builtin_amdgcn_exp2f(__builtin_fmaf(s0[r], LOG2E, -msc[jq]));
        p1[r] = __builtin_amdgcn_exp2f(__builtin_fmaf(s1[r], LOG2E, -msc[jq]));
      }
      rsum[jq] += ((p0[0] + p0[1]) + (p0[2] + p0[3])) +
                  ((p1[0] + p1[1]) + (p1[2] + p1[3]));
      uint4 up;
      up.x = (__builtin_bit_cast(unsigned int, p0[1]) & 0xFFFF0000u) |
             (__builtin_bit_cast(unsigned int, p0[0]) >> 16);
      up.y = (__builtin_bit_cast(unsigned int, p0[3]) & 0xFFFF0000u) |
             (__builtin_bit_cast(unsigned int, p0[2]) >> 16);
      up.z = (__builtin_bit_cast(unsigned int, p1[1]) & 0xFFFF0000u) |
             (__builtin_bit_cast(unsigned int, p1[0]) >> 16);
      up.w = (__builtin_bit_cast(unsigned int, p1[3]) & 0xFFFF0000u) |
             (__builtin_bit_cast(unsigned int, p1[2]) >> 16);
      v8s bp = __builtin_bit_cast(v8s, up);
#pragma unroll
      for (int ct = 0; ct < 4; ++ct)
        oacc[ct][jq] =
            __builtin_amdgcn_mfma_f32_16x16x32_bf16(aV[ct], bp, oacc[ct][jq], 0, 0, 0);
    }
  }

  // ---- epilogue ----
#pragma unroll
  for (int jq = 0; jq < 4; ++jq) {
    float s = rsum[jq];
    s += __shfl_xor(s, 16, 64);
    s += __shfl_xor(s, 32, 64);
    rsum[jq] = s;
  }
  if (quad == 0) {
#pragma unroll
    for (int jq = 0; jq < 4; ++jq)
      lred[(qg * 64 + jq * 16 + l15) * 4 + kg] = rsum[jq];
  }
  __syncthreads();
  float inv[4];
#pragma unroll
  for (int jq = 0; jq < 4; ++jq) {
    const float4 lv = *(const float4*)&lred[(qg * 64 + jq * 16 + l15) * 4];
    inv[jq] = __builtin_amdgcn_rcpf((lv.x + lv.y) + (lv.z + lv.w));
  }

  float* Obuf = (float*)smem;   // [2 qg][64 c][68 q]
#pragma unroll
  for (int round = 0; round < 4; ++round) {
    if (kg == round) {
#pragma unroll
      for (int ct = 0; ct < 4; ++ct)
#pragma unroll
        for (int jq = 0; jq < 4; ++jq)
#pragma unroll
          for (int r = 0; r < 4; ++r) {
            float val = oacc[ct][jq][r] * inv[jq];
            float* p = &Obuf[(qg * 64 + ct * 16 + quad * 4 + r) * 68 + jq * 16 + l15];
            if (round == 0) *p = val; else *p += val;
          }
    }
    __syncthreads();
  }
#pragma unroll
  for (int j = 0; j < 4; ++j) {
    int idx = tid + j * 512;
    int qg2 = idx >> 10, c = (idx >> 4) & 63, q4 = idx & 15;
    const float4 o = *(const float4*)&Obuf[(qg2 * 64 + c) * 68 + q4 * 4];
    size_t gidx = ((size_t)(b * 64 + c) << 12) + (unsigned)(qt * 128 + qg2 * 64 + q4 * 4);
    const float4 xv = *(const float4*)(x + gidx);
    float4 rv;
    rv.x = xv.x + o.x; rv.y = xv.y + o.y; rv.z = xv.z + o.z; rv.w = xv.w + o.w;
    *(float4*)(out + gidx) = rv;
  }
}

// ============ fallback (R1 kernel, proven correct) if ws too small ============
__global__ __launch_bounds__(512) void
chanattn_fallback(const float* __restrict__ x, float* __restrict__ out) {
  __shared__ __align__(16) unsigned char smem[54272];
  unsigned short* sKt = (unsigned short*)smem;
  unsigned short* sVc = (unsigned short*)(smem + 18432);
  unsigned short* sP  = (unsigned short*)(smem + 35840);
  const int tid = threadIdx.x;
  const int wave = tid >> 6, lane = tid & 63, quad = lane >> 4, l15 = lane & 15;
  const int b = blockIdx.x & 7, qt = blockIdx.x >> 3;
  const float* fb = x + (size_t)b * (64 * 4096);
  const int skey = tid & 127, sc0 = (tid >> 7) << 4;
  {
    float vq[16];
#pragma unroll
    for (int j = 0; j < 16; ++j) vq[j] = fb[(sc0 + j) * 4096 + qt * 128 + skey];
    unsigned short us[16];
#pragma unroll
    for (int j = 0; j < 16; ++j) us[j] = f2bf_rne(vq[j]);
#pragma unroll
    for (int h = 0; h < 2; ++h) {
      v8s t;
#pragma unroll
      for (int j = 0; j < 8; ++j) t[j] = (short)us[h * 8 + j];
      *(v8s*)&sKt[skey * 72 + sc0 + h * 8] = t;
    }
  }
  float vk[16];
#pragma unroll
  for (int j = 0; j < 16; ++j) vk[j] = fb[(sc0 + j) * 4096 + skey];
  __syncthreads();
  v8s aq[2];
#pragma unroll
  for (int cs = 0; cs < 2; ++cs)
    aq[cs] = *(const v8s*)&sKt[(wave * 16 + l15) * 72 + cs * 32 + quad * 8];
  __syncthreads();
  v4f oacc[4];
#pragma unroll
  for (int ct = 0; ct < 4; ++ct) oacc[ct] = (v4f){0.f, 0.f, 0.f, 0.f};
  float m_run[4], l_run[4];
#pragma unroll
  for (int r = 0; r < 4; ++r) { m_run[r] = -3.0e38f; l_run[r] = 0.f; }
  unsigned short* sPw = sP + wave * (16 * 72);
  for (int kt = 0; kt < 32; ++kt) {
    {
      unsigned short us[16];
#pragma unroll
      for (int j = 0; j < 16; ++j) us[j] = f2bf_rne(vk[j]);
#pragma unroll
      for (int h = 0; h < 2; ++h) {
        v8s t;
#pragma unroll
        for (int j = 0; j < 8; ++j) t[j] = (short)us[h * 8 + j];
        *(v8s*)&sKt[skey * 72 + sc0 + h * 8] = t;
      }
#pragma unroll
      for (int j = 0; j < 16; ++j) sVc[(sc0 + j) * 136 + skey] = us[j];
    }
    __syncthreads();
    if (kt + 1 < 32) {
      const int m0 = (kt + 1) * 128;
#pragma unroll
      for (int j = 0; j < 16; ++j) vk[j] = fb[(sc0 + j) * 4096 + m0 + skey];
    }
    v4f sacc[8];
#pragma unroll
    for (int t = 0; t < 8; ++t) {
      v4f acc = (v4f){0.f, 0.f, 0.f, 0.f};
#pragma unroll
      for (int cs = 0; cs < 2; ++cs) {
        v8s bf = *(const v8s*)&sKt[(t * 16 + l15) * 72 + cs * 32 + quad * 8];
        acc = __builtin_amdgcn_mfma_f32_16x16x32_bf16(aq[cs], bf, acc, 0, 0, 0);
      }
      sacc[t] = acc;
    }
    float alpha[4], msc[4], rsum[4];
#pragma unroll
    for (int r = 0; r < 4; ++r) {
      float mv = sacc[0][r];
#pragma unroll
      for (int t = 1; t < 8; ++t) mv = fmaxf(mv, sacc[t][r]);
      mv = fmaxf(mv, __shfl_xor(mv, 8, 64));
      mv = fmaxf(mv, __shfl_xor(mv, 4, 64));
      mv = fmaxf(mv, __shfl_xor(mv, 2, 64));
      mv = fmaxf(mv, __shfl_xor(mv, 1, 64));
      float mnew = fmaxf(m_run[r], mv);
      alpha[r] = __builtin_amdgcn_exp2f((m_run[r] - mnew) * LOG2E);
      m_run[r] = mnew;
      msc[r] = mnew * LOG2E;
      l_run[r] *= alpha[r];
      rsum[r] = 0.f;
    }
#pragma unroll
    for (int ct = 0; ct < 4; ++ct)
#pragma unroll
      for (int r = 0; r < 4; ++r) oacc[ct][r] *= alpha[r];
#pragma unroll
    for (int half = 0; half < 2; ++half) {
#pragma unroll
      for (int t = half * 4; t < half * 4 + 4; ++t)
#pragma unroll
        for (int r = 0; r < 4; ++r) {
          float p = __builtin_amdgcn_exp2f(__builtin_fmaf(sacc[t][r], LOG2E, -msc[r]));
          rsum[r] += p;
          sPw[(quad * 4 + r) * 72 + (t - half * 4) * 16 + l15] = f2bf_rne(p);
        }
      asm volatile("s_waitcnt lgkmcnt(0)" ::: "memory");
#pragma unroll
      for (int ms = 0; ms < 2; ++ms) {
        v8s af = *(const v8s*)&sPw[l15 * 72 + ms * 32 + quad * 8];
#pragma unroll
        for (int ct = 0; ct < 4; ++ct) {
          v8s bf = *(const v8s*)&sVc[(ct * 16 + l15) * 136 + (half * 2 + ms) * 32 + quad * 8];
          oacc[ct] = __builtin_amdgcn_mfma_f32_16x16x32_bf16(af, bf, oacc[ct], 0, 0, 0);
        }
      }
      asm volatile("s_waitcnt lgkmcnt(0)" ::: "memory");
    }
#pragma unroll
    for (int r = 0; r < 4; ++r) {
      float s = rsum[r];
      s += __shfl_xor(s, 8, 64);
      s += __shfl_xor(s, 4, 64);
      s += __shfl_xor(s, 2, 64);
      s += __shfl_xor(s, 1, 64);
      l_run[r] += s;
    }
    __syncthreads();
  }
  float inv[4];
#pragma unroll
  for (int r = 0; r < 4; ++r) inv[r] = __builtin_amdgcn_rcpf(l_run[r]);
  float* sOt = (float*)smem;
#pragma unroll
  for (int ct = 0; ct < 4; ++ct)
#pragma unroll
    for (int r = 0; r < 4; ++r)
      sOt[(ct * 16 + l15) * 132 + wave * 16 + quad * 4 + r] = oacc[ct][r] * inv[r];
  __syncthreads();
#pragma unroll
  for (int j = 0; j < 4; ++j) {
    int idx = tid + j * 512;
    int nv = idx & 31, c = idx >> 5;
    float4 o = *(const float4*)&sOt[c * 132 + nv * 4];
    size_t gaddr = (size_t)b * (64 * 4096) + (size_t)c * 4096 + (size_t)(qt * 128 + nv * 4);
    float4 xv = *(const float4*)(x + gaddr);
    float4 res = make_float4(xv.x + o.x, xv.y + o.y, xv.z + o.z, xv.w + o.w);
    *(float4*)(out + gaddr) = res;
  }
}

extern "C" void kernel_launch(void* const* d_in, const int* in_sizes, int n_in,
                              void* d_out, int out_size, void* d_ws, size_t ws_size,
                              hipStream_t stream) {
  const float* xin = (const float*)d_in[0];
  float* out = (float*)d_out;
  if (ws_size >= (size_t)WS_NEED) {
    unsigned short* fbf_t = (unsigned short*)((char*)d_ws + WS_FBF_T);
    unsigned short* fbf = (unsigned short*)((char*)d_ws + WS_FBF);
    float* g = (float*)((char*)d_ws + WS_G);
    float* bmax = (float*)((char*)d_ws + WS_BMAX);
    prep_kernel<<<dim3(512), dim3(256), 0, stream>>>(xin, fbf_t, fbf, g, bmax);
    chanattn_main<<<dim3(256), dim3(512), 0, stream>>>(xin, fbf_t, fbf, g, bmax, out);
  } else {
    chanattn_fallback<<<dim3(256), dim3(512), 0, stream>>>(xin, out);
  }
}